// Round 1
// baseline (157.089 us; speedup 1.0000x reference)
//
#include <hip/hip_runtime.h>
#include <math.h>

#define NB 16
#define NA 3
#define NC 80
#define GS 4096   // 64*64 spatial
#define NPOS (NB * NA * GS)   // 196608

__device__ __forceinline__ float sigmoidf_(float v) {
    return 1.0f / (1.0f + expf(-v));
}

__global__ __launch_bounds__(256) void yolo_kernel(const float* __restrict__ x,
                                                   const float* __restrict__ anchors,
                                                   float* __restrict__ out) {
    const int t = blockIdx.x * blockDim.x + threadIdx.x;  // position index over (b,a,i,j)
    if (t >= NPOS) return;
    const int s  = t & (GS - 1);      // i*64 + j
    const int ba = t >> 12;           // b*NA + a
    const int a  = ba % NA;
    const int i  = s >> 6;            // grid_x axis (row)
    const int j  = s & 63;            // grid_y axis (col)

    // input: x[b, a*85 + c, i, j] ; channel base = ba*85
    const float* xp = x + (size_t)ba * 85 * GS + s;

    const float tx = xp[0 * GS];
    const float ty = xp[1 * GS];
    const float tw = xp[2 * GS];
    const float th = xp[3 * GS];
    const float tc = xp[4 * GS];

    const float aw = anchors[a * 2 + 0];   // anchors[a][0]*g0 / scale(g0) = anchors[a][0]
    const float ah = anchors[a * 2 + 1];

    float4 box;
    box.x = (sigmoidf_(tx) + (float)i) * (1.0f / 64.0f);
    box.y = (sigmoidf_(ty) + (float)j) * (1.0f / 64.0f);
    box.z = expf(tw) * aw;
    box.w = expf(th) * ah;
    reinterpret_cast<float4*>(out)[t] = box;          // boxes: [0, NPOS*4)

    out[NPOS * 4 + t] = sigmoidf_(tc);                // conf: [NPOS*4, NPOS*5)

    // cls: [NPOS*5, NPOS*5 + NPOS*80), layout [pos][class] -> contiguous 80/pos
    float* cls = out + (size_t)NPOS * 5 + (size_t)t * NC;
    const float* xc = xp + 5 * GS;
    #pragma unroll
    for (int c = 0; c < NC; c += 4) {
        float4 v;
        v.x = sigmoidf_(xc[(c + 0) * GS]);
        v.y = sigmoidf_(xc[(c + 1) * GS]);
        v.z = sigmoidf_(xc[(c + 2) * GS]);
        v.w = sigmoidf_(xc[(c + 3) * GS]);
        *reinterpret_cast<float4*>(cls + c) = v;
    }
}

extern "C" void kernel_launch(void* const* d_in, const int* in_sizes, int n_in,
                              void* d_out, int out_size, void* d_ws, size_t ws_size,
                              hipStream_t stream) {
    const float* x       = (const float*)d_in[0];
    const float* anchors = (const float*)d_in[1];
    float* out           = (float*)d_out;
    const int threads = 256;
    const int blocks  = (NPOS + threads - 1) / threads;   // 768
    yolo_kernel<<<blocks, threads, 0, stream>>>(x, anchors, out);
}

// Round 2
// 112.885 us; speedup vs baseline: 1.3916x; 1.3916x over previous
//
#include <hip/hip_runtime.h>
#include <math.h>

#define NB 16
#define NA 3
#define NC 80
#define GS 4096                 // 64*64 spatial
#define NPOS (NB * NA * GS)     // 196608
#define LDS_S 65                // padded stride for lds[ch][p]; 65 odd -> conflict-free column writes

__device__ __forceinline__ float sigmoidf_(float v) {
    return 1.0f / (1.0f + __expf(-v));
}

// One block = one (b,a) pair x 64 consecutive spatial positions (one grid row).
// Read phase:  80 cls channels x 64 pos, coalesced over s, sigmoid -> LDS transpose tile.
// Write phase: 64x80 output tile is one contiguous 20KB region -> coalesced float4 stores.
__global__ __launch_bounds__(256) void yolo_kernel(const float* __restrict__ x,
                                                   const float* __restrict__ anchors,
                                                   float* __restrict__ out) {
    __shared__ float lds[NC * LDS_S];
    const int tid  = threadIdx.x;
    const int ba   = blockIdx.x >> 6;   // which (b,a), 0..47
    const int tile = blockIdx.x & 63;   // grid row i
    const int s0   = tile << 6;
    const float* __restrict__ xb = x + (size_t)ba * 85 * GS + s0;

    // ---- Phase B reads: coalesced loads, sigmoid, LDS[ch][p] ----
    #pragma unroll
    for (int k = 0; k < 20; ++k) {
        const int e  = tid + k * 256;   // 0..5119
        const int ch = e >> 6;
        const int p  = e & 63;
        lds[ch * LDS_S + p] = sigmoidf_(xb[(5 + ch) * GS + p]);
    }

    // ---- Phase A: wave 0 does boxes + conf (already-coalesced writes) ----
    if (tid < 64) {
        const int p = tid;
        const int t = ba * GS + s0 + p;         // global position index
        const float tx = xb[0 * GS + p];
        const float ty = xb[1 * GS + p];
        const float tw = xb[2 * GS + p];
        const float th = xb[3 * GS + p];
        const float tc = xb[4 * GS + p];
        const int a = ba % NA;
        const float aw = anchors[a * 2 + 0];    // anchors[a][0]*g0/scale(g0) = anchors[a][0]
        const float ah = anchors[a * 2 + 1];
        float4 box;
        box.x = (sigmoidf_(tx) + (float)tile) * (1.0f / 64.0f);  // grid_x = row i
        box.y = (sigmoidf_(ty) + (float)p)    * (1.0f / 64.0f);  // grid_y = col j
        box.z = __expf(tw) * aw;
        box.w = __expf(th) * ah;
        reinterpret_cast<float4*>(out)[t] = box;
        out[NPOS * 4 + t] = sigmoidf_(tc);
    }

    __syncthreads();

    // ---- Phase B writes: contiguous 5120-float tile, coalesced float4 ----
    float4* __restrict__ out4 =
        reinterpret_cast<float4*>(out + (size_t)NPOS * 5 + (size_t)(ba * GS + s0) * NC);
    #pragma unroll
    for (int k = 0; k < 5; ++k) {
        const int o4 = tid + k * 256;   // 0..1279
        const int o  = o4 * 4;
        const int p  = o / 80;
        const int ch = o - p * 80;      // multiple of 4, <= 76
        float4 v;
        v.x = lds[(ch + 0) * LDS_S + p];
        v.y = lds[(ch + 1) * LDS_S + p];
        v.z = lds[(ch + 2) * LDS_S + p];
        v.w = lds[(ch + 3) * LDS_S + p];
        out4[o4] = v;
    }
}

extern "C" void kernel_launch(void* const* d_in, const int* in_sizes, int n_in,
                              void* d_out, int out_size, void* d_ws, size_t ws_size,
                              hipStream_t stream) {
    const float* x       = (const float*)d_in[0];
    const float* anchors = (const float*)d_in[1];
    float* out           = (float*)d_out;
    const int blocks = NB * NA * 64;    // 3072 blocks, one per (b,a,row)
    yolo_kernel<<<blocks, 256, 0, stream>>>(x, anchors, out);
}